// Round 5
// baseline (289.757 us; speedup 1.0000x reference)
//
#include <hip/hip_runtime.h>
#include <hip/hip_bf16.h>
#include <type_traits>

// ---------------------------------------------------------------------------
// Problem constants
//   x: (8,128,128,256) f32   z: (8,64,64,256) f32   mask: (1,8,8,8,256,64) int
//   Wq (256,256) bq(256)  Wkv (256,512) bkv(512)  Wo (256,256) bo(256)
//   rel_table (900,8) f32   out: (8,128,128,256) f32
// ---------------------------------------------------------------------------

typedef __attribute__((ext_vector_type(8))) short short8v;     // MFMA bf16 frag (4 VGPR)
typedef __attribute__((ext_vector_type(4))) float f32x4;       // MFMA acc
typedef __attribute__((ext_vector_type(8))) unsigned short ushort8v;
typedef __attribute__((ext_vector_type(4))) unsigned short ushort4v;

#define DEV __device__ __forceinline__

DEV unsigned short f2bf(float f) {               // round-to-nearest-even f32->bf16
    union { float f; unsigned u; } v; v.f = f;
    unsigned r = v.u + 0x7FFFu + ((v.u >> 16) & 1u);
    return (unsigned short)(r >> 16);
}

DEV short8v cvt_f32x8(const float4 lo, const float4 hi) {      // 8 f32 -> 8 bf16 (RNE)
    union U { __hip_bfloat162 h[4]; short8v s; } u;
    u.h[0] = __float22bfloat162_rn(float2{lo.x, lo.y});
    u.h[1] = __float22bfloat162_rn(float2{lo.z, lo.w});
    u.h[2] = __float22bfloat162_rn(float2{hi.x, hi.y});
    u.h[3] = __float22bfloat162_rn(float2{hi.z, hi.w});
    return u.s;
}

#define ATT_SCALE 0.17677669529663687f           // 1/sqrt(32)

// ---------------------------------------------------------------------------
// Prep kernels (unchanged)
// ---------------------------------------------------------------------------
__global__ void prep_weights(const float* __restrict__ Wq, const float* __restrict__ Wkv,
                             const float* __restrict__ Wo,
                             unsigned short* __restrict__ WqT, unsigned short* __restrict__ WkvT,
                             unsigned short* __restrict__ WoT) {
    int idx = blockIdx.x * 256 + threadIdx.x;            // 262144 total
    if (idx < 65536) {
        int n = idx >> 8, k = idx & 255;
        WqT[idx] = f2bf(Wq[k * 256 + n] * ATT_SCALE);
    } else if (idx < 196608) {
        int i = idx - 65536;
        int n = i >> 8, k = i & 255;
        WkvT[i] = f2bf(Wkv[k * 512 + n]);
    } else {
        int i = idx - 196608;
        int n = i >> 8, k = i & 255;
        WoT[i] = f2bf(Wo[k * 256 + n]);
    }
}

__global__ void prep_bias(const float* __restrict__ rel_table, const float* __restrict__ bq,
                          float* __restrict__ biasb, float* __restrict__ bqs) {
    int idx = blockIdx.x * 256 + threadIdx.x;
    if (idx < 131072) {
        int head = idx >> 14;
        int q = (idx >> 6) & 255;
        int k = idx & 63;
        int qi = q >> 4, qj = q & 15;
        int ki = k >> 3, kj = k & 7;
        int r0 = qi - 2 * ki + 14, r1 = qj - 2 * kj + 14;
        biasb[idx] = rel_table[(r0 * 30 + r1) * 8 + head];
    } else if (idx < 131328) {
        int i = idx - 131072;
        bqs[i] = bq[i] * ATT_SCALE;
    }
}

__global__ void prep_mask(const int* __restrict__ mask, unsigned long long* __restrict__ mp) {
    int idx = blockIdx.x * 256 + threadIdx.x;            // 131072 rows
    const int4* src = reinterpret_cast<const int4*>(mask + (size_t)idx * 64);
    unsigned long long bits = 0;
#pragma unroll
    for (int c = 0; c < 16; ++c) {
        int4 v = src[c];
        if (v.x) bits |= 1ull << (c * 4 + 0);
        if (v.y) bits |= 1ull << (c * 4 + 1);
        if (v.z) bits |= 1ull << (c * 4 + 2);
        if (v.w) bits |= 1ull << (c * 4 + 3);
    }
    mp[idx] = bits;
}

// ---------------------------------------------------------------------------
// GEMM v5 "occupancy": C[M][N] = A[M][K=256]*B + bias, B^T row-major bf16.
// Block = 256 thr (4 waves), tile M=128 x N=64, K=256 whole.
// B panel 64x256 bf16 = 32KB LDS, staged ONCE (slot-XOR swizzle, 0-conflict),
// single barrier. Wave = 32m x 64n (mt=2, nt=4), acc = 32 VGPR.
// A streamed global->reg, named ping-pong scalars (no arrays -> no spill),
// f32 converted via v_cvt_pk. ~90 VGPR -> 5 waves/SIMD; LDS -> 5 blocks/CU.
// A re-read x4 across n-blocks is L3-absorbed (x fits in 256MB L3).
// ---------------------------------------------------------------------------
template <bool AF32, bool OUT_BF16>
__global__ __launch_bounds__(256) void gemm_v5(
    const void* __restrict__ Ain, const unsigned short* __restrict__ BT,
    const float* __restrict__ bias, void* __restrict__ Cout,
    int M, int N)
{
    __shared__ __align__(16) unsigned char Bs[32768];    // [8 kt][64 row][64 B]
    const float* Af = (const float*)Ain;
    const unsigned short* Ab = (const unsigned short*)Ain;

    const int tid = threadIdx.x;
    const int w = tid >> 6, lane = tid & 63, lr = lane & 15, lg = lane >> 4;
    const int nb = blockIdx.x * 64;
    const int mb = blockIdx.y * 128;
    const int wm = mb + w * 32;                          // wave rows [wm, wm+32)

    // ---- stage B panel once: thread -> 128B (2 kt-chunks of one row) ----
    {
        int r = tid >> 2, p = tid & 3;
        const unsigned short* src = BT + (size_t)(nb + r) * 256 + p * 64;
        int rsw = (r >> 1) & 3;
#pragma unroll
        for (int h = 0; h < 2; ++h) {
            int kt = p * 2 + h;
#pragma unroll
            for (int sl = 0; sl < 4; ++sl) {
                ushort8v v = *reinterpret_cast<const ushort8v*>(src + h * 32 + sl * 8);
                *reinterpret_cast<ushort8v*>(
                    &Bs[kt * 4096 + r * 64 + ((sl ^ rsw) << 4)]) = v;
            }
        }
    }
    __syncthreads();                                     // the ONLY barrier

    const int swz = (lg ^ ((lr >> 1) & 3)) << 4;         // lane-constant read swizzle

    f32x4 acc[2][4];
#pragma unroll
    for (int i = 0; i < 2; ++i)
#pragma unroll
        for (int j = 0; j < 4; ++j) acc[i][j] = {0.f, 0.f, 0.f, 0.f};

    if constexpr (AF32) {
        const float* A0 = Af + (size_t)(wm + lr) * 256 + lg * 8;
        const float* A1 = Af + (size_t)(wm + 16 + lr) * 256 + lg * 8;
        float4 p00, p01, p10, p11, q00, q01, q10, q11;   // named: no spillable arrays

#define LD_P(kt) { p00 = *reinterpret_cast<const float4*>(A0 + (kt) * 32);     \
                   p01 = *reinterpret_cast<const float4*>(A0 + (kt) * 32 + 4); \
                   p10 = *reinterpret_cast<const float4*>(A1 + (kt) * 32);     \
                   p11 = *reinterpret_cast<const float4*>(A1 + (kt) * 32 + 4); }
#define LD_Q(kt) { q00 = *reinterpret_cast<const float4*>(A0 + (kt) * 32);     \
                   q01 = *reinterpret_cast<const float4*>(A0 + (kt) * 32 + 4); \
                   q10 = *reinterpret_cast<const float4*>(A1 + (kt) * 32);     \
                   q11 = *reinterpret_cast<const float4*>(A1 + (kt) * 32 + 4); }
#define STEP(x00, x01, x10, x11, kt) {                                          \
        short8v a0 = cvt_f32x8(x00, x01), a1 = cvt_f32x8(x10, x11);             \
        _Pragma("unroll")                                                       \
        for (int nt = 0; nt < 4; ++nt) {                                        \
            short8v bf = *reinterpret_cast<const short8v*>(                     \
                &Bs[(kt) * 4096 + (nt * 16 + lr) * 64 + swz]);                  \
            acc[0][nt] = __builtin_amdgcn_mfma_f32_16x16x32_bf16(a0, bf, acc[0][nt], 0, 0, 0); \
            acc[1][nt] = __builtin_amdgcn_mfma_f32_16x16x32_bf16(a1, bf, acc[1][nt], 0, 0, 0); \
        } }

        LD_P(0);
#pragma unroll
        for (int kk = 0; kk < 8; kk += 2) {
            if (kk + 1 < 8) LD_Q(kk + 1);
            STEP(p00, p01, p10, p11, kk);
            if (kk + 2 < 8) LD_P(kk + 2);
            if (kk + 1 < 8) STEP(q00, q01, q10, q11, kk + 1);
        }
#undef LD_P
#undef LD_Q
#undef STEP
    } else {
        const unsigned short* A0 = Ab + (size_t)(wm + lr) * 256 + lg * 8;
        const unsigned short* A1 = Ab + (size_t)(wm + 16 + lr) * 256 + lg * 8;
        short8v p0, p1, q0, q1;

#define LD_P(kt) { p0 = *reinterpret_cast<const short8v*>(A0 + (kt) * 32);  \
                   p1 = *reinterpret_cast<const short8v*>(A1 + (kt) * 32); }
#define LD_Q(kt) { q0 = *reinterpret_cast<const short8v*>(A0 + (kt) * 32);  \
                   q1 = *reinterpret_cast<const short8v*>(A1 + (kt) * 32); }
#define STEP(x0, x1, kt) {                                                      \
        _Pragma("unroll")                                                       \
        for (int nt = 0; nt < 4; ++nt) {                                        \
            short8v bf = *reinterpret_cast<const short8v*>(                     \
                &Bs[(kt) * 4096 + (nt * 16 + lr) * 64 + swz]);                  \
            acc[0][nt] = __builtin_amdgcn_mfma_f32_16x16x32_bf16(x0, bf, acc[0][nt], 0, 0, 0); \
            acc[1][nt] = __builtin_amdgcn_mfma_f32_16x16x32_bf16(x1, bf, acc[1][nt], 0, 0, 0); \
        } }

        LD_P(0);
#pragma unroll
        for (int kk = 0; kk < 8; kk += 2) {
            if (kk + 1 < 8) LD_Q(kk + 1);
            STEP(p0, p1, kk);
            if (kk + 2 < 8) LD_P(kk + 2);
            if (kk + 1 < 8) STEP(q0, q1, kk + 1);
        }
#undef LD_P
#undef LD_Q
#undef STEP
    }

    // ---- epilogue ----
#pragma unroll
    for (int mt = 0; mt < 2; ++mt)
#pragma unroll
        for (int nt = 0; nt < 4; ++nt)
#pragma unroll
            for (int j = 0; j < 4; ++j) {
                int row = wm + mt * 16 + lg * 4 + j;
                int col = nb + nt * 16 + lr;
                float v = acc[mt][nt][j] + bias[col];
                if constexpr (OUT_BF16)
                    ((unsigned short*)Cout)[(size_t)row * N + col] = f2bf(v);
                else
                    ((float*)Cout)[(size_t)row * N + col] = v;
            }
}

// ---------------------------------------------------------------------------
// Fused window attention (unchanged from R1/R2).
// ---------------------------------------------------------------------------
__global__ __launch_bounds__(256) void win_attn(
    unsigned short* __restrict__ Qbuf,            // [8*128*128, 256] bf16 (in/out)
    const unsigned short* __restrict__ KVbuf,     // [8*64*64, 512] bf16
    const unsigned long long* __restrict__ maskp, // [8][64][256] packed bits
    const float* __restrict__ biasb)              // [8][256][64]
{
    __shared__ __align__(16) unsigned char Pb[256 * 128];   // P, 64-wide XOR-swizzled
    __shared__ __align__(16) unsigned short Vt[32][72];     // V^T: [dk][key]

    const int tid = threadIdx.x;
    const int win = blockIdx.x, head = blockIdx.y, b = blockIdx.z;
    const int wi = win >> 3, wj = win & 7;
    const int w = tid >> 6, lane = tid & 63, lr = lane & 15, lg = lane >> 4;
    const int qb = w * 64;

    {
        int key = tid & 63, c = tid >> 6;
        int kr = (wi * 8 + (key >> 3) + 4) & 63;
        int kc = (wj * 8 + (key & 7) + 4) & 63;
        ushort8v v = *reinterpret_cast<const ushort8v*>(
            KVbuf + ((size_t)(b * 4096 + kr * 64 + kc)) * 512 + 256 + head * 32 + c * 8);
#pragma unroll
        for (int e = 0; e < 8; ++e) Vt[c * 8 + e][key] = v[e];
    }

    short8v qf[4], kf[4];
#pragma unroll
    for (int mt = 0; mt < 4; ++mt) {
        int q = qb + mt * 16 + lr;
        int gr = (wi * 16 + (q >> 4) + 8) & 127;
        int gc = (wj * 16 + (q & 15) + 8) & 127;
        qf[mt] = *reinterpret_cast<const short8v*>(
            Qbuf + ((size_t)(b * 16384 + gr * 128 + gc)) * 256 + head * 32 + lg * 8);
    }
#pragma unroll
    for (int nt = 0; nt < 4; ++nt) {
        int key = nt * 16 + lr;
        int kr = (wi * 8 + (key >> 3) + 4) & 63;
        int kc = (wj * 8 + (key & 7) + 4) & 63;
        kf[nt] = *reinterpret_cast<const short8v*>(
            KVbuf + ((size_t)(b * 4096 + kr * 64 + kc)) * 512 + head * 32 + lg * 8);
    }

    f32x4 s[4][4];
#pragma unroll
    for (int mt = 0; mt < 4; ++mt)
#pragma unroll
        for (int nt = 0; nt < 4; ++nt) s[mt][nt] = {0.f, 0.f, 0.f, 0.f};
    __builtin_amdgcn_s_setprio(1);
#pragma unroll
    for (int mt = 0; mt < 4; ++mt)
#pragma unroll
        for (int nt = 0; nt < 4; ++nt)
            s[mt][nt] = __builtin_amdgcn_mfma_f32_16x16x32_bf16(qf[mt], kf[nt], s[mt][nt], 0, 0, 0);
    __builtin_amdgcn_s_setprio(0);

    const unsigned long long* mrow = maskp + (size_t)(head * 64 + win) * 256;
#pragma unroll
    for (int mt = 0; mt < 4; ++mt) {
#pragma unroll
        for (int j = 0; j < 4; ++j) {
            int q = qb + mt * 16 + lg * 4 + j;
            unsigned long long mb = mrow[q];
            const float* brow = biasb + (size_t)(head * 256 + q) * 64;
            float v[4];
            float m = -3.0e38f;
#pragma unroll
            for (int nt = 0; nt < 4; ++nt) {
                int key = nt * 16 + lr;
                float sv = s[mt][nt][j] + brow[key];
                if ((mb >> key) & 1ull) sv = -1.0e9f;
                v[nt] = sv;
                m = fmaxf(m, sv);
            }
#pragma unroll
            for (int d = 1; d < 16; d <<= 1) m = fmaxf(m, __shfl_xor(m, d, 64));
            float sum = 0.f;
#pragma unroll
            for (int nt = 0; nt < 4; ++nt) { v[nt] = __expf(v[nt] - m); sum += v[nt]; }
#pragma unroll
            for (int d = 1; d < 16; d <<= 1) sum += __shfl_xor(sum, d, 64);
            float inv = 1.0f / sum;
            int sw = (q & 7) << 4;
#pragma unroll
            for (int nt = 0; nt < 4; ++nt) {
                int off = q * 128 + (((nt * 16 + lr) * 2) ^ sw);
                *reinterpret_cast<unsigned short*>(Pb + off) = f2bf(v[nt] * inv);
            }
        }
    }

    __syncthreads();

    f32x4 o[4][2];
#pragma unroll
    for (int mt = 0; mt < 4; ++mt)
#pragma unroll
        for (int nt = 0; nt < 2; ++nt) o[mt][nt] = {0.f, 0.f, 0.f, 0.f};
#pragma unroll
    for (int kc = 0; kc < 2; ++kc) {
        short8v pf[4], vf[2];
#pragma unroll
        for (int mt = 0; mt < 4; ++mt) {
            int row = qb + mt * 16 + lr;
            int coff = (kc * 64 + lg * 16) ^ ((row & 7) << 4);
            pf[mt] = *reinterpret_cast<const short8v*>(Pb + row * 128 + coff);
        }
#pragma unroll
        for (int nt = 0; nt < 2; ++nt)
            vf[nt] = *reinterpret_cast<const short8v*>(&Vt[nt * 16 + lr][kc * 32 + lg * 8]);
        __builtin_amdgcn_s_setprio(1);
#pragma unroll
        for (int mt = 0; mt < 4; ++mt)
#pragma unroll
            for (int nt = 0; nt < 2; ++nt)
                o[mt][nt] = __builtin_amdgcn_mfma_f32_16x16x32_bf16(pf[mt], vf[nt], o[mt][nt], 0, 0, 0);
        __builtin_amdgcn_s_setprio(0);
    }

#pragma unroll
    for (int mt = 0; mt < 4; ++mt)
#pragma unroll
        for (int j = 0; j < 4; ++j) {
            int q = qb + mt * 16 + lg * 4 + j;
            int gr = (wi * 16 + (q >> 4) + 8) & 127;
            int gc = (wj * 16 + (q & 15) + 8) & 127;
            unsigned short* dst =
                Qbuf + ((size_t)(b * 16384 + gr * 128 + gc)) * 256 + head * 32;
#pragma unroll
            for (int nt = 0; nt < 2; ++nt)
                dst[nt * 16 + lr] = f2bf(o[mt][nt][j]);
        }
}

// ---------------------------------------------------------------------------
extern "C" void kernel_launch(void* const* d_in, const int* in_sizes, int n_in,
                              void* d_out, int out_size, void* d_ws, size_t ws_size,
                              hipStream_t stream) {
    const float* x    = (const float*)d_in[0];
    const float* z    = (const float*)d_in[1];
    const int*   mask = (const int*)d_in[2];
    const float* Wq   = (const float*)d_in[3];
    const float* bq   = (const float*)d_in[4];
    const float* Wkv  = (const float*)d_in[5];
    const float* bkv  = (const float*)d_in[6];
    const float* Wo   = (const float*)d_in[7];
    const float* bo   = (const float*)d_in[8];
    const float* rel  = (const float*)d_in[9];
    float* out = (float*)d_out;

    // workspace layout (~103 MB)
    char* ws = (char*)d_ws;
    unsigned short*     Qbuf  = (unsigned short*)(ws);                 // 67,108,864 B
    unsigned short*     KVbuf = (unsigned short*)(ws + 67108864);      // 33,554,432 B
    unsigned short*     WqT   = (unsigned short*)(ws + 100663296);     //    131,072 B
    unsigned short*     WkvT  = (unsigned short*)(ws + 100794368);     //    262,144 B
    unsigned short*     WoT   = (unsigned short*)(ws + 101056512);     //    131,072 B
    float*              biasb = (float*)(ws + 101187584);              //    524,288 B
    unsigned long long* maskp = (unsigned long long*)(ws + 101711872); //  1,048,576 B
    float*              bqs   = (float*)(ws + 102760448);              //      1,024 B

    prep_weights<<<1024, 256, 0, stream>>>(Wq, Wkv, Wo, WqT, WkvT, WoT);
    prep_bias<<<513, 256, 0, stream>>>(rel, bq, biasb, bqs);
    prep_mask<<<512, 256, 0, stream>>>(mask, maskp);

    // Q = x @ (Wq*scale) + bq*scale  -> bf16 [131072, 256]
    gemm_v5<true, true><<<dim3(4, 1024), 256, 0, stream>>>(
        (const void*)x, WqT, bqs, (void*)Qbuf, 131072, 256);
    // KV = z @ Wkv + bkv -> bf16 [32768, 512]
    gemm_v5<true, true><<<dim3(8, 256), 256, 0, stream>>>(
        (const void*)z, WkvT, bkv, (void*)KVbuf, 32768, 512);
    // fused window attention (in-place into Qbuf)
    win_attn<<<dim3(64, 8, 8), 256, 0, stream>>>(Qbuf, KVbuf, maskp, biasb);
    // out = attn @ Wo + bo -> f32
    gemm_v5<false, false><<<dim3(4, 1024), 256, 0, stream>>>(
        (const void*)Qbuf, WoT, bo, (void*)out, 131072, 256);
}

// Round 6
// 264.828 us; speedup vs baseline: 1.0941x; 1.0941x over previous
//
#include <hip/hip_runtime.h>
#include <hip/hip_bf16.h>
#include <type_traits>

// ---------------------------------------------------------------------------
// Problem constants
//   x: (8,128,128,256) f32   z: (8,64,64,256) f32   mask: (1,8,8,8,256,64) int
//   Wq (256,256) bq(256)  Wkv (256,512) bkv(512)  Wo (256,256) bo(256)
//   rel_table (900,8) f32   out: (8,128,128,256) f32
// ---------------------------------------------------------------------------

typedef __attribute__((ext_vector_type(8))) short short8v;     // MFMA bf16 frag
typedef __attribute__((ext_vector_type(4))) float f32x4;       // MFMA acc
typedef __attribute__((ext_vector_type(8))) unsigned short ushort8v;
typedef __attribute__((ext_vector_type(4))) unsigned short ushort4v;
typedef unsigned long long u64;

#define DEV __device__ __forceinline__

DEV unsigned short f2bf(float f) {               // round-to-nearest-even f32->bf16
    union { float f; unsigned u; } v; v.f = f;
    unsigned r = v.u + 0x7FFFu + ((v.u >> 16) & 1u);
    return (unsigned short)(r >> 16);
}

DEV short8v cvt_f32x8(const float4 lo, const float4 hi) {      // 8 f32 -> 8 bf16
    union U { __hip_bfloat162 h[4]; short8v s; } u;
    u.h[0] = __float22bfloat162_rn(float2{lo.x, lo.y});
    u.h[1] = __float22bfloat162_rn(float2{lo.z, lo.w});
    u.h[2] = __float22bfloat162_rn(float2{hi.x, hi.y});
    u.h[3] = __float22bfloat162_rn(float2{hi.z, hi.w});
    return u.s;
}

DEV uint2 pack4(f32x4 v) {                       // 4 f32 -> 4 bf16 (8 B)
    union { __hip_bfloat162 h; unsigned u; } a, b;
    a.h = __float22bfloat162_rn(float2{v[0], v[1]});
    b.h = __float22bfloat162_rn(float2{v[2], v[3]});
    return uint2{a.u, b.u};
}

#define ATT_SCALE 0.17677669529663687f           // 1/sqrt(32)

// ---------------------------------------------------------------------------
// Prep kernels (unchanged)
// ---------------------------------------------------------------------------
__global__ void prep_weights(const float* __restrict__ Wq, const float* __restrict__ Wkv,
                             const float* __restrict__ Wo,
                             unsigned short* __restrict__ WqT, unsigned short* __restrict__ WkvT,
                             unsigned short* __restrict__ WoT) {
    int idx = blockIdx.x * 256 + threadIdx.x;            // 262144 total
    if (idx < 65536) {
        int n = idx >> 8, k = idx & 255;
        WqT[idx] = f2bf(Wq[k * 256 + n] * ATT_SCALE);
    } else if (idx < 196608) {
        int i = idx - 65536;
        int n = i >> 8, k = i & 255;
        WkvT[i] = f2bf(Wkv[k * 512 + n]);
    } else {
        int i = idx - 196608;
        int n = i >> 8, k = i & 255;
        WoT[i] = f2bf(Wo[k * 256 + n]);
    }
}

__global__ void prep_bias(const float* __restrict__ rel_table, const float* __restrict__ bq,
                          float* __restrict__ biasb, float* __restrict__ bqs) {
    int idx = blockIdx.x * 256 + threadIdx.x;
    if (idx < 131072) {
        int head = idx >> 14;
        int q = (idx >> 6) & 255;
        int k = idx & 63;
        int qi = q >> 4, qj = q & 15;
        int ki = k >> 3, kj = k & 7;
        int r0 = qi - 2 * ki + 14, r1 = qj - 2 * kj + 14;
        biasb[idx] = rel_table[(r0 * 30 + r1) * 8 + head];
    } else if (idx < 131328) {
        int i = idx - 131072;
        bqs[i] = bq[i] * ATT_SCALE;
    }
}

__global__ void prep_mask(const int* __restrict__ mask, u64* __restrict__ mp) {
    int idx = blockIdx.x * 256 + threadIdx.x;            // 131072 rows
    const int4* src = reinterpret_cast<const int4*>(mask + (size_t)idx * 64);
    u64 bits = 0;
#pragma unroll
    for (int c = 0; c < 16; ++c) {
        int4 v = src[c];
        if (v.x) bits |= 1ull << (c * 4 + 0);
        if (v.y) bits |= 1ull << (c * 4 + 1);
        if (v.z) bits |= 1ull << (c * 4 + 2);
        if (v.w) bits |= 1ull << (c * 4 + 3);
    }
    mp[idx] = bits;
}

// ---------------------------------------------------------------------------
// KV-proj GEMM (R3's double-buffered gemm_proj, f32-A path, bf16 out).
// ---------------------------------------------------------------------------
__global__ __launch_bounds__(256) void gemm_kv(
    const float* __restrict__ Af, const unsigned short* __restrict__ BT,
    const float* __restrict__ bias, unsigned short* __restrict__ Cout,
    int M, int N, int K)
{
    __shared__ __align__(16) unsigned char As[2][8192];   // 128 rows x 64B
    __shared__ __align__(16) unsigned char Bs[2][8192];

    const int tid = threadIdx.x;
    const int mb = blockIdx.y * 128, nb = blockIdx.x * 128;
    const int w = tid >> 6, lane = tid & 63, lr = lane & 15, lg = lane >> 4;
    const int wm = (w >> 1) * 64, wn = (w & 1) * 64;

    const int cr0 = (w << 5) + (lane >> 2);
    const int csp = lane & 3;
    const int cs0 = csp ^ ((cr0 >> 1) & 3);
    const int cs1 = csp ^ (((cr0 + 16) >> 1) & 3);

    auto stageB = [&](int buf, int kb) {
        __builtin_amdgcn_global_load_lds(
            (const __attribute__((address_space(1))) void*)(BT + (size_t)(nb + cr0) * K + kb + cs0 * 8),
            (__attribute__((address_space(3))) void*)(&Bs[buf][w << 11]), 16, 0, 0);
        __builtin_amdgcn_global_load_lds(
            (const __attribute__((address_space(1))) void*)(BT + (size_t)(nb + cr0 + 16) * K + kb + cs1 * 8),
            (__attribute__((address_space(3))) void*)(&Bs[buf][(w << 11) + 1024]), 16, 0, 0);
    };

    float4 areg[2][2];
    auto loadA = [&](int kb) {
#pragma unroll
        for (int i = 0; i < 2; ++i) {
            int flat = tid + (i << 8);
            int r = flat >> 2, sp = flat & 3;
            int s = sp ^ ((r >> 1) & 3);
            const float* src = Af + (size_t)(mb + r) * K + kb + s * 8;
            areg[i][0] = *reinterpret_cast<const float4*>(src);
            areg[i][1] = *reinterpret_cast<const float4*>(src + 4);
        }
    };
    auto writeA = [&](int buf) {
#pragma unroll
        for (int i = 0; i < 2; ++i) {
            int flat = tid + (i << 8);
            int r = flat >> 2, sp = flat & 3;
            ushort8v u = { f2bf(areg[i][0].x), f2bf(areg[i][0].y),
                           f2bf(areg[i][0].z), f2bf(areg[i][0].w),
                           f2bf(areg[i][1].x), f2bf(areg[i][1].y),
                           f2bf(areg[i][1].z), f2bf(areg[i][1].w) };
            *reinterpret_cast<ushort8v*>(&As[buf][r * 64 + sp * 16]) = u;
        }
    };
    auto rdA = [&](int buf, int row) -> short8v {
        int swz = (lg ^ ((row >> 1) & 3)) << 4;
        return *reinterpret_cast<const short8v*>(&As[buf][row * 64 + swz]);
    };
    auto rdB = [&](int buf, int row) -> short8v {
        int swz = (lg ^ ((row >> 1) & 3)) << 4;
        return *reinterpret_cast<const short8v*>(&Bs[buf][row * 64 + swz]);
    };

    f32x4 acc[4][4];
#pragma unroll
    for (int i = 0; i < 4; ++i)
#pragma unroll
        for (int j = 0; j < 4; ++j) acc[i][j] = {0.f, 0.f, 0.f, 0.f};

    loadA(0); stageB(0, 0); writeA(0);
    __syncthreads();

    const int NT = K >> 5;
    int cur = 0;
    for (int t = 0; t < NT; ++t) {
        if (t + 1 < NT) { loadA((t + 1) << 5); stageB(cur ^ 1, (t + 1) << 5); }
        short8v af[4], bfr[4];
#pragma unroll
        for (int mt = 0; mt < 4; ++mt) af[mt] = rdA(cur, wm + mt * 16 + lr);
#pragma unroll
        for (int nt = 0; nt < 4; ++nt) bfr[nt] = rdB(cur, wn + nt * 16 + lr);
#pragma unroll
        for (int mt = 0; mt < 4; ++mt)
#pragma unroll
            for (int nt = 0; nt < 4; ++nt)
                acc[mt][nt] = __builtin_amdgcn_mfma_f32_16x16x32_bf16(
                    af[mt], bfr[nt], acc[mt][nt], 0, 0, 0);
        if (t + 1 < NT) writeA(cur ^ 1);
        __syncthreads();
        cur ^= 1;
    }

#pragma unroll
    for (int mt = 0; mt < 4; ++mt)
#pragma unroll
        for (int nt = 0; nt < 4; ++nt)
#pragma unroll
            for (int j = 0; j < 4; ++j) {
                int row = mb + wm + mt * 16 + lg * 4 + j;
                int col = nb + wn + nt * 16 + lr;
                Cout[(size_t)row * N + col] = f2bf(acc[mt][nt][j] + bias[col]);
            }
}

// ---------------------------------------------------------------------------
// Mega-fused kernel: Q-proj + 8-head window attention + O-proj.
// Block = (qblk 0..3, win 0..63, b 0..7), 256 thr / 4 waves; 64 q rows/block.
// Swapped-operand MFMA throughout: D[n][q] with q = lane&15 -> packed 8B LDS
// writes, 2-shfl softmax reduce. LDS planes (all [rows][64B], XOR slot swz):
//   Qs/Os: 8 planes (d-chunk) x [64 q]   = 32 KB   (O overwrites Q per head)
//   Vt:    2 planes (key-chunk) x [256 d] = 32 KB
//   Ps:    2 planes (key-chunk) x [64 q]  =  8 KB    total 72 KB, 2 blocks/CU
// Phase 1: waves split N (64 cols each), W-frags direct from L2.
// Phase 2: waves split q (16 rows each), all 8 heads, barrier-free.
// Phase 3: waves split N again. Exactly 2 __syncthreads total.
// ---------------------------------------------------------------------------
__global__ __launch_bounds__(256, 2) void fused_attn(
    const float* __restrict__ x, const unsigned short* __restrict__ KVbuf,
    const unsigned short* __restrict__ WqT, const unsigned short* __restrict__ WoT,
    const float* __restrict__ bqs, const float* __restrict__ bo,
    const u64* __restrict__ maskp, const float* __restrict__ biasb,
    float* __restrict__ out)
{
    __shared__ __align__(16) unsigned char L[73728];
    // Qs/Os: L + kt*4096           kt = 0..7   [64 q][64 B]
    // Vt:    L + 32768 + kc*16384  kc = 0..1   [256 d][64 B]
    // Ps:    L + 65536 + kc*4096   kc = 0..1   [64 q][64 B]

    const int tid = threadIdx.x;
    const int w = tid >> 6, lane = tid & 63, lr = lane & 15, lg = lane >> 4;
    const int qblk = blockIdx.x, win = blockIdx.y, b = blockIdx.z;
    const int wi = win >> 3, wj = win & 7;

    // ---- stage V^T (cooperative; covered by barrier 1) ----
    {
        int key = tid & 63, c = tid >> 6;
        int kr = (wi * 8 + (key >> 3) + 4) & 63;
        int kc = (wj * 8 + (key & 7) + 4) & 63;
        const unsigned short* vsrc =
            KVbuf + ((size_t)(b * 4096 + kr * 64 + kc)) * 512 + 256 + c * 64;
        unsigned char* vt = L + 32768 + (key >> 5) * 16384;
        const int klby = (key & 31) * 2;
#pragma unroll
        for (int i = 0; i < 8; ++i) {
            ushort8v v = *reinterpret_cast<const ushort8v*>(vsrc + i * 8);
#pragma unroll
            for (int e = 0; e < 8; ++e) {
                int d = c * 64 + i * 8 + e;
                *reinterpret_cast<unsigned short*>(
                    vt + d * 64 + (klby ^ (((d >> 1) & 3) << 4))) = (unsigned short)v[e];
            }
        }
    }

    // ---- phase 1: Q = x @ Wq(scaled) + bq.  Wave owns n in [w*64, w*64+64) ----
    f32x4 acc[16];
#pragma unroll
    for (int i = 0; i < 16; ++i) acc[i] = {0.f, 0.f, 0.f, 0.f};

    const unsigned short* wqb = WqT + (size_t)(w * 64 + lr) * 256 + lg * 8;
    const float* xr[4];
#pragma unroll
    for (int qt = 0; qt < 4; ++qt) {
        int gr = (wi * 16 + qblk * 4 + qt + 8) & 127;
        int gc = (wj * 16 + lr + 8) & 127;
        xr[qt] = x + ((size_t)((b * 128 + gr) * 128 + gc)) * 256 + lg * 8;
    }
#pragma unroll
    for (int kt = 0; kt < 8; ++kt) {
        short8v wqf[4], xf[4];
#pragma unroll
        for (int nt = 0; nt < 4; ++nt)
            wqf[nt] = *reinterpret_cast<const short8v*>(wqb + nt * 4096 + kt * 32);
#pragma unroll
        for (int qt = 0; qt < 4; ++qt) {
            float4 lo = *reinterpret_cast<const float4*>(xr[qt] + kt * 32);
            float4 hi = *reinterpret_cast<const float4*>(xr[qt] + kt * 32 + 4);
            xf[qt] = cvt_f32x8(lo, hi);
        }
#pragma unroll
        for (int nt = 0; nt < 4; ++nt)
#pragma unroll
            for (int qt = 0; qt < 4; ++qt)
                acc[nt * 4 + qt] = __builtin_amdgcn_mfma_f32_16x16x32_bf16(
                    wqf[nt], xf[qt], acc[nt * 4 + qt], 0, 0, 0);
    }
    // epilogue: +bq, pack to bf16, write Qs planes
#pragma unroll
    for (int nt = 0; nt < 4; ++nt) {
        int n0 = w * 64 + nt * 16 + lg * 4;
        f32x4 bq4 = *reinterpret_cast<const f32x4*>(bqs + n0);
        unsigned char* pl = L + (w * 2 + (nt >> 1)) * 4096;
        int cby = (nt & 1) * 32 + lg * 8;
#pragma unroll
        for (int qt = 0; qt < 4; ++qt) {
            int qr = qt * 16 + lr;
            uint2 pk = pack4(acc[nt * 4 + qt] + bq4);
            *reinterpret_cast<uint2*>(pl + qr * 64 + (cby ^ (((qr >> 1) & 3) << 4))) = pk;
        }
    }
    __syncthreads();                                     // barrier 1

    // ---- phase 2: attention, wave owns q-stripe [w*16, w*16+16) ----
    const int qrow = w * 16 + lr;
    const int qg = qblk * 64 + qrow;
    const int swzq = ((qrow >> 1) & 3) << 4;
    const unsigned short* kp[4];
#pragma unroll
    for (int nt = 0; nt < 4; ++nt) {
        int key = nt * 16 + lr;
        int kr = (wi * 8 + (key >> 3) + 4) & 63;
        int kc = (wj * 8 + (key & 7) + 4) & 63;
        kp[nt] = KVbuf + ((size_t)(b * 4096 + kr * 64 + kc)) * 512 + lg * 8;
    }
    const float* bb = biasb + (size_t)qg * 64 + lg * 4;
    const u64* mrow = maskp + (size_t)win * 256 + qg;

#pragma unroll
    for (int h = 0; h < 8; ++h) {
        short8v qf = *reinterpret_cast<const short8v*>(
            L + h * 4096 + qrow * 64 + ((lg << 4) ^ swzq));
        f32x4 s[4];
#pragma unroll
        for (int nt = 0; nt < 4; ++nt) {
            short8v kf = *reinterpret_cast<const short8v*>(kp[nt] + h * 32);
            f32x4 z = {0.f, 0.f, 0.f, 0.f};
            s[nt] = __builtin_amdgcn_mfma_f32_16x16x32_bf16(kf, qf, z, 0, 0, 0);
        }
        u64 mb = mrow[(size_t)h * 16384];
        float vv[16];
        float m = -3.0e38f;
#pragma unroll
        for (int nt = 0; nt < 4; ++nt) {
            f32x4 b4 = *reinterpret_cast<const f32x4*>(bb + h * 16384 + nt * 16);
#pragma unroll
            for (int j = 0; j < 4; ++j) {
                float sv = s[nt][j] + b4[j];
                if ((mb >> (nt * 16 + lg * 4 + j)) & 1ull) sv = -1.0e9f;
                vv[nt * 4 + j] = sv;
                m = fmaxf(m, sv);
            }
        }
        m = fmaxf(m, __shfl_xor(m, 16, 64));
        m = fmaxf(m, __shfl_xor(m, 32, 64));
        float sum = 0.f;
#pragma unroll
        for (int i = 0; i < 16; ++i) { vv[i] = __expf(vv[i] - m); sum += vv[i]; }
        sum += __shfl_xor(sum, 16, 64);
        sum += __shfl_xor(sum, 32, 64);
        float inv = 1.0f / sum;
        // P -> Ps planes (packed 8B per nt)
#pragma unroll
        for (int nt = 0; nt < 4; ++nt) {
            f32x4 pv = { vv[nt * 4 + 0] * inv, vv[nt * 4 + 1] * inv,
                         vv[nt * 4 + 2] * inv, vv[nt * 4 + 3] * inv };
            uint2 pk = pack4(pv);
            *reinterpret_cast<uint2*>(
                L + 65536 + (nt >> 1) * 4096 + qrow * 64 +
                ((((nt & 1) * 32 + lg * 8)) ^ swzq)) = pk;
        }
        // O_h = P V_h  (K=64 over 2 key-chunks)
        f32x4 o[2];
        o[0] = {0.f, 0.f, 0.f, 0.f}; o[1] = {0.f, 0.f, 0.f, 0.f};
#pragma unroll
        for (int kcp = 0; kcp < 2; ++kcp) {
            short8v pf = *reinterpret_cast<const short8v*>(
                L + 65536 + kcp * 4096 + qrow * 64 + ((lg << 4) ^ swzq));
#pragma unroll
            for (int nt2 = 0; nt2 < 2; ++nt2) {
                int d = h * 32 + nt2 * 16 + lr;
                short8v vf = *reinterpret_cast<const short8v*>(
                    L + 32768 + kcp * 16384 + d * 64 + ((lg << 4) ^ (((d >> 1) & 3) << 4)));
                o[nt2] = __builtin_amdgcn_mfma_f32_16x16x32_bf16(vf, pf, o[nt2], 0, 0, 0);
            }
        }
        // O slice -> Qs plane h (plane h's S-read already done, same wave)
#pragma unroll
        for (int nt2 = 0; nt2 < 2; ++nt2) {
            uint2 pk = pack4(o[nt2]);
            *reinterpret_cast<uint2*>(
                L + h * 4096 + qrow * 64 + ((nt2 * 32 + lg * 8) ^ swzq)) = pk;
        }
    }
    __syncthreads();                                     // barrier 2

    // ---- phase 3: out = O @ Wo + bo.  Wave owns n in [w*64, w*64+64) ----
#pragma unroll
    for (int i = 0; i < 16; ++i) acc[i] = {0.f, 0.f, 0.f, 0.f};
    const unsigned short* wob = WoT + (size_t)(w * 64 + lr) * 256 + lg * 8;
#pragma unroll
    for (int kt = 0; kt < 8; ++kt) {
        short8v wof[4], of[4];
#pragma unroll
        for (int nt = 0; nt < 4; ++nt)
            wof[nt] = *reinterpret_cast<const short8v*>(wob + nt * 4096 + kt * 32);
#pragma unroll
        for (int qt = 0; qt < 4; ++qt) {
            int qr = qt * 16 + lr;
            of[qt] = *reinterpret_cast<const short8v*>(
                L + kt * 4096 + qr * 64 + ((lg << 4) ^ (((qr >> 1) & 3) << 4)));
        }
#pragma unroll
        for (int nt = 0; nt < 4; ++nt)
#pragma unroll
            for (int qt = 0; qt < 4; ++qt)
                acc[nt * 4 + qt] = __builtin_amdgcn_mfma_f32_16x16x32_bf16(
                    wof[nt], of[qt], acc[nt * 4 + qt], 0, 0, 0);
    }
#pragma unroll
    for (int nt = 0; nt < 4; ++nt) {
        int n0 = w * 64 + nt * 16 + lg * 4;
        f32x4 bo4 = *reinterpret_cast<const f32x4*>(bo + n0);
#pragma unroll
        for (int qt = 0; qt < 4; ++qt) {
            int gr = (wi * 16 + qblk * 4 + qt + 8) & 127;
            int gc = (wj * 16 + lr + 8) & 127;
            f32x4 v = acc[nt * 4 + qt] + bo4;
            *reinterpret_cast<f32x4*>(
                out + ((size_t)((b * 128 + gr) * 128 + gc)) * 256 + n0) = v;
        }
    }
}

// ---------------------------------------------------------------------------
extern "C" void kernel_launch(void* const* d_in, const int* in_sizes, int n_in,
                              void* d_out, int out_size, void* d_ws, size_t ws_size,
                              hipStream_t stream) {
    const float* x    = (const float*)d_in[0];
    const float* z    = (const float*)d_in[1];
    const int*   mask = (const int*)d_in[2];
    const float* Wq   = (const float*)d_in[3];
    const float* bq   = (const float*)d_in[4];
    const float* Wkv  = (const float*)d_in[5];
    const float* bkv  = (const float*)d_in[6];
    const float* Wo   = (const float*)d_in[7];
    const float* bo   = (const float*)d_in[8];
    const float* rel  = (const float*)d_in[9];
    float* out = (float*)d_out;

    // workspace layout (~35.7 MB)
    char* ws = (char*)d_ws;
    unsigned short* KVbuf = (unsigned short*)(ws);                 // 33,554,432 B
    unsigned short* WqT   = (unsigned short*)(ws + 33554432);      //    131,072 B
    unsigned short* WkvT  = (unsigned short*)(ws + 33685504);      //    262,144 B
    unsigned short* WoT   = (unsigned short*)(ws + 33947648);      //    131,072 B
    float*          biasb = (float*)(ws + 34078720);               //    524,288 B
    u64*            maskp = (u64*)(ws + 34603008);                 //  1,048,576 B
    float*          bqs   = (float*)(ws + 35651584);               //      1,024 B

    prep_weights<<<1024, 256, 0, stream>>>(Wq, Wkv, Wo, WqT, WkvT, WoT);
    prep_bias<<<513, 256, 0, stream>>>(rel, bq, biasb, bqs);
    prep_mask<<<512, 256, 0, stream>>>(mask, maskp);

    // KV = z @ Wkv + bkv -> bf16 [32768, 512]
    gemm_kv<<<dim3(4, 256), 256, 0, stream>>>(z, WkvT, bkv, KVbuf, 32768, 512, 256);

    // fused Q-proj + window attention + O-proj
    fused_attn<<<dim3(4, 64, 8), 256, 0, stream>>>(
        x, KVbuf, WqT, WoT, bqs, bo, maskp, biasb, out);
}